// Round 11
// baseline (302.116 us; speedup 1.0000x reference)
//
#include <hip/hip_runtime.h>

// Problem constants
#define B_Q   4096
#define E_DIM 512
#define N_C   2000
#define N_P   64000

// GEMM geometry: 256x256 tile, BK=64 (2 K-halves of 32), 8 waves (2M x 4N),
// double-buffered 128 KiB LDS, 16x16x32 MFMA.
// Round 11: 4-phase iteration (32 MFMA per barrier-pair) COMBINED with
// dual-set tail-prefetched fragments + SGB interleave.  r8 proved the
// per-phase scaffolding amortizes at 32 MFMA/phase; r9/r10 machinery makes
// the 12 fragment reads non-blocking (overlapped with the MFMA burst).
#define BM 256
#define BN 256

typedef __bf16 bf16x8 __attribute__((ext_vector_type(8)));
typedef float  f32x4  __attribute__((ext_vector_type(4)));

__device__ __forceinline__ unsigned short f2bf(float f) {
  unsigned u = __builtin_bit_cast(unsigned, f);
  u += 0x7fffu + ((u >> 16) & 1u);
  return (unsigned short)(u >> 16);
}

__device__ __forceinline__ void async_ld16(const void* g, void* l) {
  __builtin_amdgcn_global_load_lds(
      (const __attribute__((address_space(1))) void*)g,
      (__attribute__((address_space(3))) void*)l,
      16, 0, 0);
}

// ---------------------------------------------------------------------------
// Row L2-normalize fp32 -> bf16 for BOTH inputs in one launch.
// ---------------------------------------------------------------------------
__global__ __launch_bounds__(128) void norm_rows_kernel(
    const float* __restrict__ w1, const float* __restrict__ data,
    unsigned short* __restrict__ wbf, unsigned short* __restrict__ dbf)
{
  int row = blockIdx.x;
  const float* in;
  unsigned short* outbf;
  if (row < N_P) { in = w1; outbf = wbf; }
  else           { in = data; outbf = dbf; row -= N_P; }
  const int tid = threadIdx.x;
  const float4 v = *(const float4*)(in + (size_t)row * E_DIM + tid * 4);
  float ss = v.x*v.x + v.y*v.y + v.z*v.z + v.w*v.w;
  #pragma unroll
  for (int s = 1; s < 64; s <<= 1) ss += __shfl_xor(ss, s);
  __shared__ float partial[2];
  if ((tid & 63) == 0) partial[tid >> 6] = ss;
  __syncthreads();
  const float tot = partial[0] + partial[1];
  const float inv = 1.0f / fmaxf(sqrtf(tot), 1e-12f);
  ushort4 o;
  o.x = f2bf(v.x * inv); o.y = f2bf(v.y * inv);
  o.z = f2bf(v.z * inv); o.w = f2bf(v.w * inv);
  *(ushort4*)(outbf + (size_t)row * E_DIM + tid * 4) = o;
}

// ---------------------------------------------------------------------------
// LDS: A[buf][h][256 rows][4 x 16B] @0, B same @65536; region = 16 KiB.
// Chunk swizzle: slot (row,cc) holds global chunk cc ^ ((row>>1)&3); stager
// pre-swizzles the GLOBAL source chunk, LDS dest stays linear.
//
// 4-phase iteration over k-tile pair (t on buf0, t+1 on buf1); each phase
// stages one (A+B) region pair (4 instr) and computes one (buf,h) = 32 MFMA:
//   P1 (0,h0): stage A+B(1,1,t+1)   P2 (0,h1): stage A+B(0,0,t+2)
//   P3 (1,h0): stage A+B(0,1,t+2)   P4 (1,h1): stage A+B(1,0,t+3)
// Tail of phase p reads ALL 12 frags (8 A + 4 B) of phase p+1's region into
// the alternate register set, interleaved with the 32 MFMA via SGB.
// vmcnt ledger (verified r8 ledger, tail-guard re-derived): WAITV(8) at
// every phase head (after stage, outstanding=12) retires exactly the region
// this phase's TAIL reads:
//   P1 tail (0,1): staged prev-P3 -> retired by P1 WAITV(8)
//   P2 tail (1,0): staged prev-P4 -> retired by P2 WAITV(8)
//   P3 tail (1,1): staged cur-P1  -> retired by P3 WAITV(8)
//   P4 tail (0,0)': staged cur-P2 -> retired by P4 WAITV(8)
// WAR: a region's last reads (tail of phase q) drain at q's end lgkmcnt(0)
// before q's end barrier; its restage is >= 1 full phase later.  End
// lgkmcnt(0) costs ~0: last tail DS issues with 8 MFMA (~155 cyc) to follow,
// > the ~120 cyc ds_read latency.
// No head lgkm: all MFMA deps drained by the PREVIOUS phase's end drain.
// Drain iter (t=6): P1 stages (1,1,7)+WAITV(8); P2 WAITV(4); P3 WAITV(0).
// ---------------------------------------------------------------------------
#define WAITV(N) asm volatile("s_waitcnt vmcnt(" #N ")" ::: "memory")
#define LGKM0    asm volatile("s_waitcnt lgkmcnt(0)" ::: "memory")
#define SBAR     asm volatile("s_barrier" ::: "memory")
#define NOPS     do {} while (0)

#define STAGE_A(BUF,H,KOFF) do { \
  async_ld16(gA + (KOFF)*64 + (H)*32,         smem + (BUF)*32768 + (H)*16384 + sdst); \
  async_ld16(gA + 65536 + (KOFF)*64 + (H)*32, smem + (BUF)*32768 + (H)*16384 + sdst + 8192); \
} while(0)

#define STAGE_B(BUF,H,KOFF) do { \
  async_ld16(gB + (KOFF)*64 + (H)*32,         smem + 65536 + (BUF)*32768 + (H)*16384 + sdst); \
  async_ld16(gB + 65536 + (KOFF)*64 + (H)*32, smem + 65536 + (BUF)*32768 + (H)*16384 + sdst + 8192); \
} while(0)

#define STAGE_AB(BUF,H,KOFF) do { STAGE_A(BUF,H,KOFF); STAGE_B(BUF,H,KOFF); } while(0)

// Dual-set fragments: set S = phase parity.  8 A frags (both MH halves) +
// 4 B frags per region.
#define RDA8(S,BUF,H) do { \
  a##S##_0 = *(const bf16x8*)(pa + (BUF)*32768 + (H)*16384 + 0*1024); \
  a##S##_1 = *(const bf16x8*)(pa + (BUF)*32768 + (H)*16384 + 1*1024); \
  a##S##_2 = *(const bf16x8*)(pa + (BUF)*32768 + (H)*16384 + 2*1024); \
  a##S##_3 = *(const bf16x8*)(pa + (BUF)*32768 + (H)*16384 + 3*1024); \
  a##S##_4 = *(const bf16x8*)(pa + (BUF)*32768 + (H)*16384 + 4*1024); \
  a##S##_5 = *(const bf16x8*)(pa + (BUF)*32768 + (H)*16384 + 5*1024); \
  a##S##_6 = *(const bf16x8*)(pa + (BUF)*32768 + (H)*16384 + 6*1024); \
  a##S##_7 = *(const bf16x8*)(pa + (BUF)*32768 + (H)*16384 + 7*1024); \
} while(0)

#define RDB4(S,BUF,H) do { \
  b##S##_0 = *(const bf16x8*)(pb + (BUF)*32768 + (H)*16384 +    0); \
  b##S##_1 = *(const bf16x8*)(pb + (BUF)*32768 + (H)*16384 + 1024); \
  b##S##_2 = *(const bf16x8*)(pb + (BUF)*32768 + (H)*16384 + 2048); \
  b##S##_3 = *(const bf16x8*)(pb + (BUF)*32768 + (H)*16384 + 3072); \
} while(0)

#define MM(S,m,n) \
  acc[m][n] = __builtin_amdgcn_mfma_f32_16x16x32_bf16( \
      a##S##_##m, b##S##_##n, acc[m][n], 0, 0, 0)

#define MFMA32(S) do { \
  MM(S,0,0); MM(S,0,1); MM(S,0,2); MM(S,0,3); \
  MM(S,1,0); MM(S,1,1); MM(S,1,2); MM(S,1,3); \
  MM(S,2,0); MM(S,2,1); MM(S,2,2); MM(S,2,3); \
  MM(S,3,0); MM(S,3,1); MM(S,3,2); MM(S,3,3); \
  MM(S,4,0); MM(S,4,1); MM(S,4,2); MM(S,4,3); \
  MM(S,5,0); MM(S,5,1); MM(S,5,2); MM(S,5,3); \
  MM(S,6,0); MM(S,6,1); MM(S,6,2); MM(S,6,3); \
  MM(S,7,0); MM(S,7,1); MM(S,7,2); MM(S,7,3); \
} while(0)

// sched_group_barrier interleave (LLVM masks: MFMA=0x8, DS_READ=0x100).
#define SGB(M,N) __builtin_amdgcn_sched_group_barrier(M, N, 0)
// 12 tail reads among 32 MFMA: {MFMA x2, DS_READ x1} x12, then MFMA x8.
#define ILV12 do { \
  SGB(0x8,2); SGB(0x100,1); SGB(0x8,2); SGB(0x100,1); \
  SGB(0x8,2); SGB(0x100,1); SGB(0x8,2); SGB(0x100,1); \
  SGB(0x8,2); SGB(0x100,1); SGB(0x8,2); SGB(0x100,1); \
  SGB(0x8,2); SGB(0x100,1); SGB(0x8,2); SGB(0x100,1); \
  SGB(0x8,2); SGB(0x100,1); SGB(0x8,2); SGB(0x100,1); \
  SGB(0x8,2); SGB(0x100,1); SGB(0x8,2); SGB(0x100,1); \
  SGB(0x8,8); \
} while(0)

// Phase: stage next region pair, counted vmcnt wait (guards THIS phase's
// tail reads), barrier, pin (no hoisting), 32 MFMA on set S interleaved
// with next phase's 12 tail reads (set S^1), WAR lgkm drain, end barrier.
#define PH(S, STAGE, WAIT, TAIL, ILV) do { \
  STAGE; \
  WAIT; \
  SBAR; \
  __builtin_amdgcn_sched_barrier(0); \
  __builtin_amdgcn_s_setprio(1); \
  MFMA32(S); \
  TAIL; \
  ILV; \
  LGKM0; \
  __builtin_amdgcn_s_setprio(0); \
  SBAR; \
} while(0)

__global__ __launch_bounds__(512, 2) void gemm_max_kernel(
    const unsigned short* __restrict__ wbf,   // [64000][512] bf16, normalized
    const unsigned short* __restrict__ dbf,   // [4096][512]  bf16, normalized
    float* __restrict__ out)                  // [2000][4096]
{
  extern __shared__ char smem[];              // 131072 B

  const int tid  = threadIdx.x;
  const int lane = tid & 63;
  const int wid  = tid >> 6;      // 0..7
  const int wr   = wid >> 2;      // 0..1  (128 rows each)
  const int wc   = wid & 3;       // 0..3  (64 cols each)

  // XCD-aware swizzle: 4000 blocks, 8 XCDs, 500/chunk (bijective).
  const int bid  = blockIdx.x;
  const int wgid = (bid & 7) * 500 + (bid >> 3);
  const int rowb = wgid >> 4;     // 0..249
  const int colb = wgid & 15;     // 0..15
  const int rowBase = rowb * BM;
  const int colBase = colb * BN;

  // Staging: region = 256 rows x 32 shorts = 1024 x 16B chunks; thread t
  // handles chunks t (rows 0-127) and t+512 (rows 128-255).
  const int srow = tid >> 2;
  const int gch  = (tid & 3) ^ ((tid >> 3) & 3);   // pre-swizzled global chunk
  const unsigned short* gA = wbf + (size_t)(rowBase + srow) * E_DIM + gch * 8;
  const unsigned short* gB = dbf + (size_t)(colBase + srow) * E_DIM + gch * 8;
  const int sdst = tid * 16;      // linear LDS dest

  // Fragment read bases (swizzled chunk) -- identical to round 2 (0 conflicts)
  const int r   = lane & 15;
  const int kg  = lane >> 4;
  const int swz = (kg ^ ((r >> 1) & 3)) * 16;
  const char* pa = smem + (wr * 128 + r) * 64 + swz;
  const char* pb = smem + 65536 + (wc * 64 + r) * 64 + swz;

  f32x4 acc[8][4];
  #pragma unroll
  for (int m = 0; m < 8; ++m)
    #pragma unroll
    for (int n = 0; n < 4; ++n)
      acc[m][n] = (f32x4){0.f, 0.f, 0.f, 0.f};

  bf16x8 a0_0, a0_1, a0_2, a0_3, a0_4, a0_5, a0_6, a0_7;
  bf16x8 a1_0, a1_1, a1_2, a1_3, a1_4, a1_5, a1_6, a1_7;
  bf16x8 b0_0, b0_1, b0_2, b0_3, b1_0, b1_1, b1_2, b1_3;

  // Prologue: 12 loads (regions 0.h0, 0.h1, 1.h0); WAITV(8) retires the
  // first 4 = region (0,0); pre-read its 12 fragments into set 0.
  STAGE_AB(0,0,0);
  STAGE_AB(0,1,0);
  STAGE_AB(1,0,1);
  WAITV(8);
  SBAR;
  RDA8(0, 0,0);
  RDB4(0, 0,0);

  #pragma unroll 1
  for (int kt = 0; kt < 6; kt += 2) {
    PH(0, STAGE_AB(1,1,kt+1), WAITV(8), RDA8(1,0,1); RDB4(1,0,1), ILV12);
    PH(1, STAGE_AB(0,0,kt+2), WAITV(8), RDA8(0,1,0); RDB4(0,1,0), ILV12);
    PH(0, STAGE_AB(0,1,kt+2), WAITV(8), RDA8(1,1,1); RDB4(1,1,1), ILV12);
    PH(1, STAGE_AB(1,0,kt+3), WAITV(8), RDA8(0,0,0); RDB4(0,0,0), ILV12);
  }
  // Drain iteration (kt=6, tiles 6/7): only (1,1,7) left to stage.
  PH(0, STAGE_AB(1,1,7), WAITV(8), RDA8(1,0,1); RDB4(1,0,1), ILV12);
  PH(1, NOPS,            WAITV(4), RDA8(0,1,0); RDB4(0,1,0), ILV12);
  PH(0, NOPS,            WAITV(0), RDA8(1,1,1); RDB4(1,1,1), ILV12);
  PH(1, NOPS,            NOPS,     NOPS,                     NOPS);

  // Epilogue: per-class max (class = 32 rows = m-pair).  Wave row =
  // wr*128 + m*16 + kg*4 + j; reduce m-pair x j, then across kg (lanes).
  const int classBase = rowb * 8 + wr * 4;
  #pragma unroll
  for (int q = 0; q < 4; ++q) {
    #pragma unroll
    for (int n = 0; n < 4; ++n) {
      float pm = -3.4e38f;
      #pragma unroll
      for (int j = 0; j < 4; ++j)
        pm = fmaxf(pm, fmaxf(acc[2*q][n][j], acc[2*q+1][n][j]));
      pm = fmaxf(pm, __shfl_xor(pm, 16));
      pm = fmaxf(pm, __shfl_xor(pm, 32));
      if (lane < 16)
        out[(size_t)(classBase + q) * B_Q + colBase + wc * 64 + n * 16 + r] = pm;
    }
  }
}

// ---------------------------------------------------------------------------
extern "C" void kernel_launch(void* const* d_in, const int* in_sizes, int n_in,
                              void* d_out, int out_size, void* d_ws, size_t ws_size,
                              hipStream_t stream) {
  const float* data = (const float*)d_in[0];   // [4096][512]
  const float* w1   = (const float*)d_in[1];   // [64000][512]
  float* out = (float*)d_out;                  // [2000][4096]

  unsigned short* wbf = (unsigned short*)d_ws;
  unsigned short* dbf = wbf + (size_t)N_P * E_DIM;

  (void)hipFuncSetAttribute((const void*)gemm_max_kernel,
      hipFuncAttributeMaxDynamicSharedMemorySize, 131072);

  norm_rows_kernel<<<N_P + B_Q, 128, 0, stream>>>(w1, data, wbf, dbf);
  gemm_max_kernel<<<4000, 512, 131072, stream>>>(wbf, dbf, out);
}

// Round 12
// 191.638 us; speedup vs baseline: 1.5765x; 1.5765x over previous
//
#include <hip/hip_runtime.h>

// Problem constants
#define B_Q   4096
#define E_DIM 512
#define N_C   2000
#define N_P   64000

// Round 12: int8 port of the round-10 kernel (best bf16 = 253us, MfmaUtil 49).
// Per-row-scaled symmetric int8 quantization of the L2-normalized rows;
// mfma_i32_16x16x64_i8 (2x bf16 rate, K=64/instr) halves MFMA instructions,
// LDS fragment reads, staged bytes, and HBM fetch.  The r10 8-phase schedule,
// LDS byte layout (16 KB regions, 4x16B chunks/row, XOR swizzle), vmcnt
// ledger, balanced-6 tail reads and SGB interleave map BYTE-IDENTICALLY;
// only element interpretation and k-tile count (4 instead of 8) change.
// Epilogue: y = max_p(idot_p * wsc_p) * dsc_b  (row scales before class-max).
#define BM 256
#define BN 256

typedef int i32x4 __attribute__((ext_vector_type(4)));

__device__ __forceinline__ void async_ld16(const void* g, void* l) {
  __builtin_amdgcn_global_load_lds(
      (const __attribute__((address_space(1))) void*)g,
      (__attribute__((address_space(3))) void*)l,
      16, 0, 0);
}

// ---------------------------------------------------------------------------
// Row L2-normalize + per-row-scaled int8 quantization, both inputs.
// q_i = round(v_i * inv_norm * 127 / m),  m = max_i |v_i * inv_norm|;
// sc[row] = m / 127  (dequant factor).
// ---------------------------------------------------------------------------
__global__ __launch_bounds__(128) void normq_kernel(
    const float* __restrict__ w1, const float* __restrict__ data,
    signed char* __restrict__ wq, signed char* __restrict__ dq,
    float* __restrict__ wsc, float* __restrict__ dsc)
{
  int row = blockIdx.x;
  const float* in; signed char* outq; float* sc;
  if (row < N_P) { in = w1;   outq = wq; sc = wsc; }
  else           { in = data; outq = dq; sc = dsc; row -= N_P; }
  const int tid = threadIdx.x;
  const float4 v = *(const float4*)(in + (size_t)row * E_DIM + tid * 4);
  float ss = v.x*v.x + v.y*v.y + v.z*v.z + v.w*v.w;
  float am = fmaxf(fmaxf(fabsf(v.x), fabsf(v.y)), fmaxf(fabsf(v.z), fabsf(v.w)));
  #pragma unroll
  for (int s = 1; s < 64; s <<= 1) {
    ss += __shfl_xor(ss, s);
    am = fmaxf(am, __shfl_xor(am, s));
  }
  __shared__ float pss[2], pam[2];
  if ((tid & 63) == 0) { pss[tid >> 6] = ss; pam[tid >> 6] = am; }
  __syncthreads();
  const float inv = 1.0f / fmaxf(sqrtf(pss[0] + pss[1]), 1e-12f);
  const float m   = fmaxf(fmaxf(pam[0], pam[1]) * inv, 1e-20f);
  const float qs  = 127.0f / m * inv;          // v * qs in [-127, 127]
  char4 o;
  o.x = (signed char)__float2int_rn(v.x * qs);
  o.y = (signed char)__float2int_rn(v.y * qs);
  o.z = (signed char)__float2int_rn(v.z * qs);
  o.w = (signed char)__float2int_rn(v.w * qs);
  *(char4*)(outq + (size_t)row * E_DIM + tid * 4) = o;
  if (tid == 0) sc[row] = m * (1.0f / 127.0f);
}

// ---------------------------------------------------------------------------
// LDS (bytes, identical to r10): A[buf][h][256 rows][4 x 16B] @0, B @65536;
// region = 16 KiB (h = K-half of 64 int8 elements); buf stride 32768,
// h stride 16384.  Chunk swizzle: slot (row,cc) holds global chunk
// cc ^ ((row>>1)&3); stager pre-swizzles the GLOBAL source chunk.
// k-tiles: 4 of BK=128 elements (= 128 B/row).  Staging ledger and balanced
// tail-read schedule identical to r10 (verified): one main ii-block (tiles
// 0,1) + drain ii-block (tiles 2,3); WAITV(6) at odd phases, drain 6/4/0.
// ---------------------------------------------------------------------------
#define WAITV(N) asm volatile("s_waitcnt vmcnt(" #N ")" ::: "memory")
#define SBAR     asm volatile("s_barrier" ::: "memory")
#define NOPS     do {} while (0)

#define STAGE_A(BUF,H,KOFF) do { \
  async_ld16(gA + (KOFF)*128 + (H)*64,         smem + (BUF)*32768 + (H)*16384 + sdst); \
  async_ld16(gA + 65536 + (KOFF)*128 + (H)*64, smem + (BUF)*32768 + (H)*16384 + sdst + 8192); \
} while(0)

#define STAGE_B(BUF,H,KOFF) do { \
  async_ld16(gB + (KOFF)*128 + (H)*64,         smem + 65536 + (BUF)*32768 + (H)*16384 + sdst); \
  async_ld16(gB + 65536 + (KOFF)*128 + (H)*64, smem + 65536 + (BUF)*32768 + (H)*16384 + sdst + 8192); \
} while(0)

// Fragment-register double buffering: A sets alternate every phase,
// B sets alternate every 2 phases; B reads split 2+2 over two tails.
#define RDA(S,BUF,H,MH) do { \
  a##S##_0 = *(const i32x4*)(pa + (BUF)*32768 + (H)*16384 + ((MH)*4+0)*1024); \
  a##S##_1 = *(const i32x4*)(pa + (BUF)*32768 + (H)*16384 + ((MH)*4+1)*1024); \
  a##S##_2 = *(const i32x4*)(pa + (BUF)*32768 + (H)*16384 + ((MH)*4+2)*1024); \
  a##S##_3 = *(const i32x4*)(pa + (BUF)*32768 + (H)*16384 + ((MH)*4+3)*1024); \
} while(0)

#define RDB01(S,BUF,H) do { \
  b##S##_0 = *(const i32x4*)(pb + (BUF)*32768 + (H)*16384 +    0); \
  b##S##_1 = *(const i32x4*)(pb + (BUF)*32768 + (H)*16384 + 1024); \
} while(0)

#define RDB23(S,BUF,H) do { \
  b##S##_2 = *(const i32x4*)(pb + (BUF)*32768 + (H)*16384 + 2048); \
  b##S##_3 = *(const i32x4*)(pb + (BUF)*32768 + (H)*16384 + 3072); \
} while(0)

#define MM(AS,BS,MH,m,n) \
  acc[(MH)*4+m][n] = __builtin_amdgcn_mfma_i32_16x16x64_i8( \
      a##AS##_##m, b##BS##_##n, acc[(MH)*4+m][n], 0, 0, 0)

#define MFMA16(AS,BS,MH) do { \
  MM(AS,BS,MH,0,0); MM(AS,BS,MH,0,1); MM(AS,BS,MH,0,2); MM(AS,BS,MH,0,3); \
  MM(AS,BS,MH,1,0); MM(AS,BS,MH,1,1); MM(AS,BS,MH,1,2); MM(AS,BS,MH,1,3); \
  MM(AS,BS,MH,2,0); MM(AS,BS,MH,2,1); MM(AS,BS,MH,2,2); MM(AS,BS,MH,2,3); \
  MM(AS,BS,MH,3,0); MM(AS,BS,MH,3,1); MM(AS,BS,MH,3,2); MM(AS,BS,MH,3,3); \
} while(0)

// sched_group_barrier interleave (LLVM masks: MFMA=0x8, DS_READ=0x100).
#define SGB(M,N) __builtin_amdgcn_sched_group_barrier(M, N, 0)
#define ILV6 do { \
  SGB(0x8,2); SGB(0x100,1); SGB(0x8,2); SGB(0x100,1); \
  SGB(0x8,2); SGB(0x100,1); SGB(0x8,2); SGB(0x100,1); \
  SGB(0x8,2); SGB(0x100,1); SGB(0x8,2); SGB(0x100,1); \
  SGB(0x8,4); \
} while(0)
#define ILV4 do { \
  SGB(0x8,2); SGB(0x100,1); SGB(0x8,2); SGB(0x100,1); \
  SGB(0x8,2); SGB(0x100,1); SGB(0x8,2); SGB(0x100,1); \
  SGB(0x8,8); \
} while(0)

#define PHX(AS,BS,MH, STAGE, WAIT, TAIL, ILV) do { \
  STAGE; \
  WAIT; \
  SBAR; \
  asm volatile("s_waitcnt lgkmcnt(0)" ::: "memory"); \
  __builtin_amdgcn_sched_barrier(0); \
  __builtin_amdgcn_s_setprio(1); \
  MFMA16(AS,BS,MH); \
  TAIL; \
  ILV; \
  __builtin_amdgcn_s_setprio(0); \
  SBAR; \
} while(0)

#define IIBLK(K1,K2,K3) do { \
  PHX(0,0,0, STAGE_A(1,1,K1), WAITV(6), RDA(1,0,0,1); RDB01(1,0,1), ILV6); \
  PHX(1,0,1, STAGE_B(1,1,K1), NOPS,     RDA(0,0,1,0); RDB23(1,0,1), ILV6); \
  PHX(0,1,0, STAGE_A(0,0,K2), WAITV(6), RDA(1,0,1,1); RDB01(0,1,0), ILV6); \
  PHX(1,1,1, STAGE_B(0,0,K2), NOPS,     RDA(0,1,0,0); RDB23(0,1,0), ILV6); \
  PHX(0,0,0, STAGE_A(0,1,K2), WAITV(6), RDA(1,1,0,1); RDB01(1,1,1), ILV6); \
  PHX(1,0,1, STAGE_B(0,1,K2), NOPS,     RDA(0,1,1,0); RDB23(1,1,1), ILV6); \
  PHX(0,1,0, STAGE_A(1,0,K3), WAITV(6), RDA(1,1,1,1); RDB01(0,0,0), ILV6); \
  PHX(1,1,1, STAGE_B(1,0,K3), NOPS,     RDA(0,0,0,0); RDB23(0,0,0), ILV6); \
} while(0)

__global__ __launch_bounds__(512, 2) void gemm_max_kernel(
    const signed char* __restrict__ wq,   // [64000][512] i8, row-scaled
    const signed char* __restrict__ dq,   // [4096][512]  i8, row-scaled
    const float* __restrict__ wsc,        // [64000] dequant scales
    const float* __restrict__ dsc,        // [4096]  dequant scales
    float* __restrict__ out)              // [2000][4096]
{
  extern __shared__ char smem[];          // 131072 B

  const int tid  = threadIdx.x;
  const int lane = tid & 63;
  const int wid  = tid >> 6;      // 0..7
  const int wr   = wid >> 2;      // 0..1  (128 rows each)
  const int wc   = wid & 3;       // 0..3  (64 cols each)

  // XCD-aware swizzle: 4000 blocks, 8 XCDs, 500/chunk (bijective).
  const int bid  = blockIdx.x;
  const int wgid = (bid & 7) * 500 + (bid >> 3);
  const int rowb = wgid >> 4;     // 0..249
  const int colb = wgid & 15;     // 0..15
  const int rowBase = rowb * BM;
  const int colBase = colb * BN;

  // Staging: region = 256 rows x 64 B = 1024 x 16B chunks; thread t handles
  // chunks t (rows 0-127) and t+512 (rows 128-255).  Row = 512 B (i8).
  const int srow = tid >> 2;
  const int gch  = (tid & 3) ^ ((tid >> 3) & 3);   // pre-swizzled global chunk
  const signed char* gA = wq + (size_t)(rowBase + srow) * E_DIM + gch * 16;
  const signed char* gB = dq + (size_t)(colBase + srow) * E_DIM + gch * 16;
  const int sdst = tid * 16;      // linear LDS dest

  // Fragment read bases (swizzled chunk; byte-identical to r10, 0 conflicts)
  const int r   = lane & 15;
  const int kg  = lane >> 4;
  const int swz = (kg ^ ((r >> 1) & 3)) * 16;
  const char* pa = smem + (wr * 128 + r) * 64 + swz;
  const char* pb = smem + 65536 + (wc * 64 + r) * 64 + swz;

  i32x4 acc[8][4];
  #pragma unroll
  for (int m = 0; m < 8; ++m)
    #pragma unroll
    for (int n = 0; n < 4; ++n)
      acc[m][n] = (i32x4){0, 0, 0, 0};

  i32x4 a0_0, a0_1, a0_2, a0_3, a1_0, a1_1, a1_2, a1_3;
  i32x4 b0_0, b0_1, b0_2, b0_3, b1_0, b1_1, b1_2, b1_3;

  // Prologue: 12 loads (regions 0.h0, 0.h1, 1.h0); pre-read phase-1 frags.
  STAGE_A(0,0,0); STAGE_B(0,0,0);
  STAGE_A(0,1,0); STAGE_B(0,1,0);
  STAGE_A(1,0,1); STAGE_B(1,0,1);
  WAITV(8);
  SBAR;
  RDA(0,0,0,0);
  RDB01(0,0,0);
  RDB23(0,0,0);

  // Main ii-block: k-tiles 0,1 (stages tiles 1,2,3).
  IIBLK(1,2,3);
  // Drain ii-block: k-tiles 2,3; only (1,1,3) left to stage; waits 6/4/0.
  PHX(0,0,0, STAGE_A(1,1,3), WAITV(6), RDA(1,0,0,1); RDB01(1,0,1), ILV6);
  PHX(1,0,1, STAGE_B(1,1,3), NOPS,     RDA(0,0,1,0); RDB23(1,0,1), ILV6);
  PHX(0,1,0, NOPS,           WAITV(4), RDA(1,0,1,1); RDB01(0,1,0), ILV6);
  PHX(1,1,1, NOPS,           NOPS,     RDA(0,1,0,0); RDB23(0,1,0), ILV6);
  PHX(0,0,0, NOPS,           WAITV(0), RDA(1,1,0,1); RDB01(1,1,1), ILV6);
  PHX(1,0,1, NOPS,           NOPS,     RDA(0,1,1,0); RDB23(1,1,1), ILV6);
  PHX(0,1,0, NOPS,           NOPS,     RDA(1,1,1,1),               ILV4);
  PHX(1,1,1, NOPS,           NOPS,     NOPS,                       NOPS);

  // Epilogue: dequant + per-class max.  Wave row = wr*128 + m*16 + kg*4 + j;
  // class = m-pair.  Apply per-row wsc BEFORE max, per-col dsc after.
  float wsv[8][4];
  {
    const float* wscp = wsc + rowBase + wr * 128 + kg * 4;
    #pragma unroll
    for (int m = 0; m < 8; ++m)
      #pragma unroll
      for (int j = 0; j < 4; ++j)
        wsv[m][j] = wscp[m * 16 + j];
  }
  float dv[4];
  {
    const float* dscp = dsc + colBase + wc * 64 + r;
    #pragma unroll
    for (int n = 0; n < 4; ++n) dv[n] = dscp[n * 16];
  }
  const int classBase = rowb * 8 + wr * 4;
  #pragma unroll
  for (int q = 0; q < 4; ++q) {
    #pragma unroll
    for (int n = 0; n < 4; ++n) {
      float pm = -3.4e38f;
      #pragma unroll
      for (int j = 0; j < 4; ++j)
        pm = fmaxf(pm, fmaxf((float)acc[2*q][n][j]   * wsv[2*q][j],
                             (float)acc[2*q+1][n][j] * wsv[2*q+1][j]));
      pm = fmaxf(pm, __shfl_xor(pm, 16));
      pm = fmaxf(pm, __shfl_xor(pm, 32));
      if (lane < 16)
        out[(size_t)(classBase + q) * B_Q + colBase + wc * 64 + n * 16 + r]
            = pm * dv[n];
    }
  }
}

// ---------------------------------------------------------------------------
extern "C" void kernel_launch(void* const* d_in, const int* in_sizes, int n_in,
                              void* d_out, int out_size, void* d_ws, size_t ws_size,
                              hipStream_t stream) {
  const float* data = (const float*)d_in[0];   // [4096][512]
  const float* w1   = (const float*)d_in[1];   // [64000][512]
  float* out = (float*)d_out;                  // [2000][4096]

  signed char* wq = (signed char*)d_ws;                       // 32.77 MB
  signed char* dq = wq + (size_t)N_P * E_DIM;                 //  2.10 MB
  float* wsc = (float*)(dq + (size_t)B_Q * E_DIM);            // 256 KB
  float* dsc = wsc + N_P;                                     //  16 KB

  (void)hipFuncSetAttribute((const void*)gemm_max_kernel,
      hipFuncAttributeMaxDynamicSharedMemorySize, 131072);

  normq_kernel<<<N_P + B_Q, 128, 0, stream>>>(w1, data, wq, dq, wsc, dsc);
  gemm_max_kernel<<<4000, 512, 131072, stream>>>(wq, dq, wsc, dsc, out);
}

// Round 13
// 185.079 us; speedup vs baseline: 1.6324x; 1.0354x over previous
//
#include <hip/hip_runtime.h>

// Problem constants
#define B_Q   4096
#define E_DIM 512
#define N_C   2000
#define N_P   64000

// Round 13: occupancy lever.  int8 GEMM (r12 numerics, verified absmax
// 2.9e-3) restructured from one 512-thread 256x256 block per CU (2 waves/
// SIMD, lockstep barriers, MfmaUtil 37%) to FOUR independent 256-thread
// 128x128 blocks per CU: wave tile 64x64 (acc 64 i32), ~115 regs -> 4
// waves/SIMD, LDS 32 KB/block.  Cross-block TLP covers the per-phase
// barrier/wait stalls that rounds 7-11 failed to hide within a wave.
#define BM 128
#define BN 128

typedef int i32x4 __attribute__((ext_vector_type(4)));

__device__ __forceinline__ void async_ld16(const void* g, void* l) {
  __builtin_amdgcn_global_load_lds(
      (const __attribute__((address_space(1))) void*)g,
      (__attribute__((address_space(3))) void*)l,
      16, 0, 0);
}

// ---------------------------------------------------------------------------
// Row L2-normalize + per-row-scaled int8 quantization, both inputs (r12).
// ---------------------------------------------------------------------------
__global__ __launch_bounds__(128) void normq_kernel(
    const float* __restrict__ w1, const float* __restrict__ data,
    signed char* __restrict__ wq, signed char* __restrict__ dq,
    float* __restrict__ wsc, float* __restrict__ dsc)
{
  int row = blockIdx.x;
  const float* in; signed char* outq; float* sc;
  if (row < N_P) { in = w1;   outq = wq; sc = wsc; }
  else           { in = data; outq = dq; sc = dsc; row -= N_P; }
  const int tid = threadIdx.x;
  const float4 v = *(const float4*)(in + (size_t)row * E_DIM + tid * 4);
  float ss = v.x*v.x + v.y*v.y + v.z*v.z + v.w*v.w;
  float am = fmaxf(fmaxf(fabsf(v.x), fabsf(v.y)), fmaxf(fabsf(v.z), fabsf(v.w)));
  #pragma unroll
  for (int s = 1; s < 64; s <<= 1) {
    ss += __shfl_xor(ss, s);
    am = fmaxf(am, __shfl_xor(am, s));
  }
  __shared__ float pss[2], pam[2];
  if ((tid & 63) == 0) { pss[tid >> 6] = ss; pam[tid >> 6] = am; }
  __syncthreads();
  const float inv = 1.0f / fmaxf(sqrtf(pss[0] + pss[1]), 1e-12f);
  const float m   = fmaxf(fmaxf(pam[0], pam[1]) * inv, 1e-20f);
  const float qs  = 127.0f / m * inv;          // v * qs in [-127, 127]
  char4 o;
  o.x = (signed char)__float2int_rn(v.x * qs);
  o.y = (signed char)__float2int_rn(v.y * qs);
  o.z = (signed char)__float2int_rn(v.z * qs);
  o.w = (signed char)__float2int_rn(v.w * qs);
  *(char4*)(outq + (size_t)row * E_DIM + tid * 4) = o;
  if (tid == 0) sc[row] = m * (1.0f / 127.0f);
}

// ---------------------------------------------------------------------------
// LDS (32768 B): A[buf][128 rows][4 x 16B] @0 (8 KB/buf), B same @16384.
// k-tile = BK=64 i8 elements = 64 B/row; 8 tiles; double-buffered (tile t in
// buf t&1).  Chunk swizzle (r12-verified, 0 conflicts): slot (row,cc) holds
// global chunk cc ^ ((row>>1)&3); stager pre-swizzles the GLOBAL chunk, LDS
// dest linear.  Thread t stages chunks t (rows 0-63) and t+256 (rows 64-127);
// both use the same pre-swizzled source chunk ((t&3)^((t>>3)&3), invariant
// under row+64).
//
// Iter t (buf b=t&1): {8 ds_read frags; lgkm(0); SBAR (all waves done with
// buf b); stage tile t+2 -> buf b (4 loads); WAITV(4) retires tile t+1's 4
// loads; SBAR (tile t+1 visible); 16 MFMA}.  Prologue stages tiles 0,1 +
// WAITV(4).  Iter 6: no stage, WAITV(0).  Iter 7: no stage/wait.
// Cross-block TLP (4 blocks/CU at different t) hides the waits.
// ---------------------------------------------------------------------------
#define WAITV(N) asm volatile("s_waitcnt vmcnt(" #N ")" ::: "memory")
#define LGKM0    asm volatile("s_waitcnt lgkmcnt(0)" ::: "memory")
#define SBAR     asm volatile("s_barrier" ::: "memory")
#define NOPS     do {} while (0)

#define STAGE_A(BUF,KOFF) do { \
  async_ld16(gA + (KOFF)*64,         smem + (BUF)*8192 + sdst); \
  async_ld16(gA + 32768 + (KOFF)*64, smem + (BUF)*8192 + sdst + 4096); \
} while(0)

#define STAGE_B(BUF,KOFF) do { \
  async_ld16(gB + (KOFF)*64,         smem + 16384 + (BUF)*8192 + sdst); \
  async_ld16(gB + 32768 + (KOFF)*64, smem + 16384 + (BUF)*8192 + sdst + 4096); \
} while(0)

#define RD(BUF) do { \
  fa0 = *(const i32x4*)(pa + (BUF)*8192 +    0); \
  fa1 = *(const i32x4*)(pa + (BUF)*8192 + 1024); \
  fa2 = *(const i32x4*)(pa + (BUF)*8192 + 2048); \
  fa3 = *(const i32x4*)(pa + (BUF)*8192 + 3072); \
  fb0 = *(const i32x4*)(pb + (BUF)*8192 +    0); \
  fb1 = *(const i32x4*)(pb + (BUF)*8192 + 1024); \
  fb2 = *(const i32x4*)(pb + (BUF)*8192 + 2048); \
  fb3 = *(const i32x4*)(pb + (BUF)*8192 + 3072); \
} while(0)

#define MM(m,n) \
  acc[m][n] = __builtin_amdgcn_mfma_i32_16x16x64_i8(fa##m, fb##n, acc[m][n], 0, 0, 0)

#define MFMA16 do { \
  MM(0,0); MM(0,1); MM(0,2); MM(0,3); \
  MM(1,0); MM(1,1); MM(1,2); MM(1,3); \
  MM(2,0); MM(2,1); MM(2,2); MM(2,3); \
  MM(3,0); MM(3,1); MM(3,2); MM(3,3); \
} while(0)

#define ITER(BUF, STAGE, WAIT) do { \
  RD(BUF); \
  LGKM0; \
  SBAR; \
  STAGE; \
  WAIT; \
  SBAR; \
  __builtin_amdgcn_s_setprio(1); \
  MFMA16; \
  __builtin_amdgcn_s_setprio(0); \
} while(0)

__global__ __launch_bounds__(256, 4) void gemm_max_kernel(
    const signed char* __restrict__ wq,   // [64000][512] i8, row-scaled
    const signed char* __restrict__ dq,   // [4096][512]  i8, row-scaled
    const float* __restrict__ wsc,        // [64000] dequant scales
    const float* __restrict__ dsc,        // [4096]  dequant scales
    float* __restrict__ out)              // [2000][4096]
{
  __shared__ __align__(16) char smem[32768];

  const int tid  = threadIdx.x;
  const int lane = tid & 63;
  const int wid  = tid >> 6;      // 0..3
  const int wr   = wid >> 1;      // 0..1  (64 rows each)
  const int wc   = wid & 1;       // 0..1  (64 cols each)

  // XCD-aware bijective chunked swizzle: 16000 blocks, 2000/XCD.
  const int bid  = blockIdx.x;
  const int wgid = (bid & 7) * 2000 + (bid >> 3);
  const int rowb = wgid >> 5;     // 0..499
  const int colb = wgid & 31;     // 0..31
  const int rowBase = rowb * BM;
  const int colBase = colb * BN;

  // Staging: region = 128 rows x 64 B = 512 chunks of 16 B; thread t handles
  // chunks t (rows 0-63) and t+256 (rows 64-127), same pre-swizzled source.
  const int srow = tid >> 2;
  const int gch  = (tid & 3) ^ ((tid >> 3) & 3);
  const signed char* gA = wq + (size_t)(rowBase + srow) * E_DIM + gch * 16;
  const signed char* gB = dq + (size_t)(colBase + srow) * E_DIM + gch * 16;
  const int sdst = tid * 16;      // linear LDS dest

  // Fragment read bases (swizzled chunk).
  const int r   = lane & 15;
  const int kg  = lane >> 4;
  const int swz = (kg ^ ((r >> 1) & 3)) * 16;
  const char* pa = smem + (wr * 64 + r) * 64 + swz;
  const char* pb = smem + 16384 + (wc * 64 + r) * 64 + swz;

  i32x4 acc[4][4];
  #pragma unroll
  for (int m = 0; m < 4; ++m)
    #pragma unroll
    for (int n = 0; n < 4; ++n)
      acc[m][n] = (i32x4){0, 0, 0, 0};

  i32x4 fa0, fa1, fa2, fa3, fb0, fb1, fb2, fb3;

  // Prologue: tiles 0 (buf0) and 1 (buf1); retire tile 0.
  STAGE_A(0,0); STAGE_B(0,0);
  STAGE_A(1,1); STAGE_B(1,1);
  WAITV(4);
  SBAR;

  ITER(0, STAGE_A(0,2); STAGE_B(0,2), WAITV(4));
  ITER(1, STAGE_A(1,3); STAGE_B(1,3), WAITV(4));
  ITER(0, STAGE_A(0,4); STAGE_B(0,4), WAITV(4));
  ITER(1, STAGE_A(1,5); STAGE_B(1,5), WAITV(4));
  ITER(0, STAGE_A(0,6); STAGE_B(0,6), WAITV(4));
  ITER(1, STAGE_A(1,7); STAGE_B(1,7), WAITV(4));
  ITER(0, NOPS,                       WAITV(0));
  ITER(1, NOPS,                       NOPS);

  // Epilogue: dequant + per-class max.  Wave row = wr*64 + m*16 + kg*4 + j;
  // class = m-pair (32 rows).  Row scales BEFORE max, col scale after.
  float wsv[4][4];
  {
    #pragma unroll
    for (int m = 0; m < 4; ++m) {
      const float4 w4 = *(const float4*)(wsc + rowBase + wr * 64 + m * 16 + kg * 4);
      wsv[m][0] = w4.x; wsv[m][1] = w4.y; wsv[m][2] = w4.z; wsv[m][3] = w4.w;
    }
  }
  float dv[4];
  {
    const float* dscp = dsc + colBase + wc * 64 + r;
    #pragma unroll
    for (int n = 0; n < 4; ++n) dv[n] = dscp[n * 16];
  }
  const int classBase = rowb * 4 + wr * 2;
  #pragma unroll
  for (int q = 0; q < 2; ++q) {
    #pragma unroll
    for (int n = 0; n < 4; ++n) {
      float pm = -3.4e38f;
      #pragma unroll
      for (int j = 0; j < 4; ++j)
        pm = fmaxf(pm, fmaxf((float)acc[2*q][n][j]   * wsv[2*q][j],
                             (float)acc[2*q+1][n][j] * wsv[2*q+1][j]));
      pm = fmaxf(pm, __shfl_xor(pm, 16));
      pm = fmaxf(pm, __shfl_xor(pm, 32));
      if (lane < 16)
        out[(size_t)(classBase + q) * B_Q + colBase + wc * 64 + n * 16 + r]
            = pm * dv[n];
    }
  }
}

// ---------------------------------------------------------------------------
extern "C" void kernel_launch(void* const* d_in, const int* in_sizes, int n_in,
                              void* d_out, int out_size, void* d_ws, size_t ws_size,
                              hipStream_t stream) {
  const float* data = (const float*)d_in[0];   // [4096][512]
  const float* w1   = (const float*)d_in[1];   // [64000][512]
  float* out = (float*)d_out;                  // [2000][4096]

  signed char* wq = (signed char*)d_ws;                       // 32.77 MB
  signed char* dq = wq + (size_t)N_P * E_DIM;                 //  2.10 MB
  float* wsc = (float*)(dq + (size_t)B_Q * E_DIM);            // 256 KB
  float* dsc = wsc + N_P;                                     //  16 KB

  normq_kernel<<<N_P + B_Q, 128, 0, stream>>>(w1, data, wq, dq, wsc, dsc);
  gemm_max_kernel<<<(N_P / BM) * (B_Q / BN), 256, 0, stream>>>(wq, dq, wsc, dsc, out);
}

// Round 15
// 183.449 us; speedup vs baseline: 1.6469x; 1.0089x over previous
//
#include <hip/hip_runtime.h>

// Problem constants
#define B_Q   4096
#define E_DIM 512
#define N_C   2000
#define N_P   64000

// Round 15: r14 (int8 128x128 4-wave + intra-wave SGB interleave of next
// iter's fragment ds_reads into the MFMA cluster) with the PROLOGUE RACE
// FIXED: r14 issued RD(0,0) (ds_reads of tile 0 in buf 0) and entered
// ITER 0's barrier+STAGE(tile2->buf0) without draining lgkm -- ds_read and
// global_load_lds LDS-writes are not mutually ordered, so tile 2 could land
// before the tile-0 reads executed (absmax 2.8e-2).  Fix: LGKM0 after the
// prologue RD, before the first ITER's barrier.  In-loop ledger already
// drains (LGKM0 precedes every SBAR1/STAGE).
#define BM 128
#define BN 128

typedef int i32x4 __attribute__((ext_vector_type(4)));

__device__ __forceinline__ void async_ld16(const void* g, void* l) {
  __builtin_amdgcn_global_load_lds(
      (const __attribute__((address_space(1))) void*)g,
      (__attribute__((address_space(3))) void*)l,
      16, 0, 0);
}

// ---------------------------------------------------------------------------
// Row L2-normalize + per-row-scaled int8 quantization, both inputs (r12).
// ---------------------------------------------------------------------------
__global__ __launch_bounds__(128) void normq_kernel(
    const float* __restrict__ w1, const float* __restrict__ data,
    signed char* __restrict__ wq, signed char* __restrict__ dq,
    float* __restrict__ wsc, float* __restrict__ dsc)
{
  int row = blockIdx.x;
  const float* in; signed char* outq; float* sc;
  if (row < N_P) { in = w1;   outq = wq; sc = wsc; }
  else           { in = data; outq = dq; sc = dsc; row -= N_P; }
  const int tid = threadIdx.x;
  const float4 v = *(const float4*)(in + (size_t)row * E_DIM + tid * 4);
  float ss = v.x*v.x + v.y*v.y + v.z*v.z + v.w*v.w;
  float am = fmaxf(fmaxf(fabsf(v.x), fabsf(v.y)), fmaxf(fabsf(v.z), fabsf(v.w)));
  #pragma unroll
  for (int s = 1; s < 64; s <<= 1) {
    ss += __shfl_xor(ss, s);
    am = fmaxf(am, __shfl_xor(am, s));
  }
  __shared__ float pss[2], pam[2];
  if ((tid & 63) == 0) { pss[tid >> 6] = ss; pam[tid >> 6] = am; }
  __syncthreads();
  const float inv = 1.0f / fmaxf(sqrtf(pss[0] + pss[1]), 1e-12f);
  const float m   = fmaxf(fmaxf(pam[0], pam[1]) * inv, 1e-20f);
  const float qs  = 127.0f / m * inv;          // v * qs in [-127, 127]
  char4 o;
  o.x = (signed char)__float2int_rn(v.x * qs);
  o.y = (signed char)__float2int_rn(v.y * qs);
  o.z = (signed char)__float2int_rn(v.z * qs);
  o.w = (signed char)__float2int_rn(v.w * qs);
  *(char4*)(outq + (size_t)row * E_DIM + tid * 4) = o;
  if (tid == 0) sc[row] = m * (1.0f / 127.0f);
}

// ---------------------------------------------------------------------------
// LDS (32768 B): A[buf][128 rows][4 x 16B] @0 (8 KB/buf), B same @16384.
// k-tile = BK=64 i8 = 64 B/row; 8 tiles double-buffered (tile t in buf t&1).
// Chunk swizzle (verified, 0 conflicts): slot (row,cc) holds global chunk
// cc ^ ((row>>1)&3); stager pre-swizzles the GLOBAL chunk, LDS dest linear.
//
// Iter t (buf b = t&1):
//   SBAR1   -- all waves' reads of buf b (tile t) drained (prev LGKM0 /
//              prologue LGKM0) -> restage of buf b safe
//   STAGE tile t+2 -> buf b (4 loads)
//   WAITV(4) -- retires tile t+1's 4 loads (per wave; SBAR2 makes global)
//   SBAR2   -- tile t+1 visible block-wide; tail reads below legal
//   setprio(1); 16 MFMA (set cur) interleaved by SGB with the 8 ds_reads of
//   tile t+1 from buf b^1 into set nxt ({M1,D1}x8 + M8 trailing cover);
//   LGKM0 (drains tail reads, before next SBAR1); setprio(0)
// Prologue: stage tiles 0,1; WAITV(4); SBAR; RD tile0 -> set0; LGKM0 (fix).
// t=6: no stage, WAITV(0); t=7: plain MFMA, no tail.
// ---------------------------------------------------------------------------
#define WAITV(N) asm volatile("s_waitcnt vmcnt(" #N ")" ::: "memory")
#define LGKM0    asm volatile("s_waitcnt lgkmcnt(0)" ::: "memory")
#define SBAR     asm volatile("s_barrier" ::: "memory")
#define NOPS     do {} while (0)

#define STAGE_A(BUF,KOFF) do { \
  async_ld16(gA + (KOFF)*64,         smem + (BUF)*8192 + sdst); \
  async_ld16(gA + 32768 + (KOFF)*64, smem + (BUF)*8192 + sdst + 4096); \
} while(0)

#define STAGE_B(BUF,KOFF) do { \
  async_ld16(gB + (KOFF)*64,         smem + 16384 + (BUF)*8192 + sdst); \
  async_ld16(gB + 32768 + (KOFF)*64, smem + 16384 + (BUF)*8192 + sdst + 4096); \
} while(0)

// Read 8 fragments of buffer BUF into register set S (0 or 1).
#define RD(S,BUF) do { \
  fa##S##0 = *(const i32x4*)(pa + (BUF)*8192 +    0); \
  fa##S##1 = *(const i32x4*)(pa + (BUF)*8192 + 1024); \
  fa##S##2 = *(const i32x4*)(pa + (BUF)*8192 + 2048); \
  fa##S##3 = *(const i32x4*)(pa + (BUF)*8192 + 3072); \
  fb##S##0 = *(const i32x4*)(pb + (BUF)*8192 +    0); \
  fb##S##1 = *(const i32x4*)(pb + (BUF)*8192 + 1024); \
  fb##S##2 = *(const i32x4*)(pb + (BUF)*8192 + 2048); \
  fb##S##3 = *(const i32x4*)(pb + (BUF)*8192 + 3072); \
} while(0)

#define MM(S,m,n) \
  acc[m][n] = __builtin_amdgcn_mfma_i32_16x16x64_i8(fa##S##m, fb##S##n, acc[m][n], 0, 0, 0)

#define MFMA16(S) do { \
  MM(S,0,0); MM(S,0,1); MM(S,0,2); MM(S,0,3); \
  MM(S,1,0); MM(S,1,1); MM(S,1,2); MM(S,1,3); \
  MM(S,2,0); MM(S,2,1); MM(S,2,2); MM(S,2,3); \
  MM(S,3,0); MM(S,3,1); MM(S,3,2); MM(S,3,3); \
} while(0)

// Interleave: {MFMA x1, DS_READ x1} x8, then MFMA x8 (cover for last read).
#define SGB(M,N) __builtin_amdgcn_sched_group_barrier(M, N, 0)
#define ILV8 do { \
  SGB(0x8,1); SGB(0x100,1); SGB(0x8,1); SGB(0x100,1); \
  SGB(0x8,1); SGB(0x100,1); SGB(0x8,1); SGB(0x100,1); \
  SGB(0x8,1); SGB(0x100,1); SGB(0x8,1); SGB(0x100,1); \
  SGB(0x8,1); SGB(0x100,1); SGB(0x8,1); SGB(0x100,1); \
  SGB(0x8,8); \
} while(0)

// S = current fragment set; tail reads go to set S^1 from buffer BUF^1.
#define ITER(S,BUF, STAGE, WAIT, TAIL, ILV) do { \
  SBAR; \
  STAGE; \
  WAIT; \
  SBAR; \
  __builtin_amdgcn_sched_barrier(0); \
  __builtin_amdgcn_s_setprio(1); \
  MFMA16(S); \
  TAIL; \
  ILV; \
  LGKM0; \
  __builtin_amdgcn_s_setprio(0); \
} while(0)

__global__ __launch_bounds__(256, 3) void gemm_max_kernel(
    const signed char* __restrict__ wq,   // [64000][512] i8, row-scaled
    const signed char* __restrict__ dq,   // [4096][512]  i8, row-scaled
    const float* __restrict__ wsc,        // [64000] dequant scales
    const float* __restrict__ dsc,        // [4096]  dequant scales
    float* __restrict__ out)              // [2000][4096]
{
  __shared__ __align__(16) char smem[32768];

  const int tid  = threadIdx.x;
  const int lane = tid & 63;
  const int wid  = tid >> 6;      // 0..3
  const int wr   = wid >> 1;      // 0..1  (64 rows each)
  const int wc   = wid & 1;       // 0..1  (64 cols each)

  // XCD-aware bijective chunked swizzle: 16000 blocks, 2000/XCD.
  const int bid  = blockIdx.x;
  const int wgid = (bid & 7) * 2000 + (bid >> 3);
  const int rowb = wgid >> 5;     // 0..499
  const int colb = wgid & 31;     // 0..31
  const int rowBase = rowb * BM;
  const int colBase = colb * BN;

  // Staging: region = 128 rows x 64 B = 512 chunks of 16 B; thread t handles
  // chunks t (rows 0-63) and t+256 (rows 64-127), same pre-swizzled source.
  const int srow = tid >> 2;
  const int gch  = (tid & 3) ^ ((tid >> 3) & 3);
  const signed char* gA = wq + (size_t)(rowBase + srow) * E_DIM + gch * 16;
  const signed char* gB = dq + (size_t)(colBase + srow) * E_DIM + gch * 16;
  const int sdst = tid * 16;      // linear LDS dest

  // Fragment read bases (swizzled chunk).
  const int r   = lane & 15;
  const int kg  = lane >> 4;
  const int swz = (kg ^ ((r >> 1) & 3)) * 16;
  const char* pa = smem + (wr * 64 + r) * 64 + swz;
  const char* pb = smem + 16384 + (wc * 64 + r) * 64 + swz;

  i32x4 acc[4][4];
  #pragma unroll
  for (int m = 0; m < 4; ++m)
    #pragma unroll
    for (int n = 0; n < 4; ++n)
      acc[m][n] = (i32x4){0, 0, 0, 0};

  i32x4 fa00, fa01, fa02, fa03, fb00, fb01, fb02, fb03;   // set 0
  i32x4 fa10, fa11, fa12, fa13, fb10, fb11, fb12, fb13;   // set 1

  // Prologue: tiles 0 (buf0) and 1 (buf1); retire tile 0; pre-read set 0;
  // DRAIN the reads before ITER 0's barrier lets STAGE overwrite buf 0.
  STAGE_A(0,0); STAGE_B(0,0);
  STAGE_A(1,1); STAGE_B(1,1);
  WAITV(4);
  SBAR;
  RD(0,0);
  LGKM0;     // <-- r14 race fix: tile-0 reads complete before restage of buf0

  // Iters t=0..7: set = t&1, buf = t&1 (coincide).  Stage tile t+2 for t<6.
  ITER(0,0, STAGE_A(0,2); STAGE_B(0,2), WAITV(4), RD(1,1), ILV8);
  ITER(1,1, STAGE_A(1,3); STAGE_B(1,3), WAITV(4), RD(0,0), ILV8);
  ITER(0,0, STAGE_A(0,4); STAGE_B(0,4), WAITV(4), RD(1,1), ILV8);
  ITER(1,1, STAGE_A(1,5); STAGE_B(1,5), WAITV(4), RD(0,0), ILV8);
  ITER(0,0, STAGE_A(0,6); STAGE_B(0,6), WAITV(4), RD(1,1), ILV8);
  ITER(1,1, STAGE_A(1,7); STAGE_B(1,7), WAITV(4), RD(0,0), ILV8);
  ITER(0,0, NOPS,                       WAITV(0), RD(1,1), ILV8);
  ITER(1,1, NOPS,                       NOPS,     NOPS,    NOPS);

  // Epilogue: dequant + per-class max.  Wave row = wr*64 + m*16 + kg*4 + j;
  // class = m-pair (32 rows).  Row scales BEFORE max, col scale after.
  float wsv[4][4];
  {
    #pragma unroll
    for (int m = 0; m < 4; ++m) {
      const float4 w4 = *(const float4*)(wsc + rowBase + wr * 64 + m * 16 + kg * 4);
      wsv[m][0] = w4.x; wsv[m][1] = w4.y; wsv[m][2] = w4.z; wsv[m][3] = w4.w;
    }
  }
  float dv[4];
  {
    const float* dscp = dsc + colBase + wc * 64 + r;
    #pragma unroll
    for (int n = 0; n < 4; ++n) dv[n] = dscp[n * 16];
  }
  const int classBase = rowb * 4 + wr * 2;
  #pragma unroll
  for (int q = 0; q < 2; ++q) {
    #pragma unroll
    for (int n = 0; n < 4; ++n) {
      float pm = -3.4e38f;
      #pragma unroll
      for (int j = 0; j < 4; ++j)
        pm = fmaxf(pm, fmaxf((float)acc[2*q][n][j]   * wsv[2*q][j],
                             (float)acc[2*q+1][n][j] * wsv[2*q+1][j]));
      pm = fmaxf(pm, __shfl_xor(pm, 16));
      pm = fmaxf(pm, __shfl_xor(pm, 32));
      if (lane < 16)
        out[(size_t)(classBase + q) * B_Q + colBase + wc * 64 + n * 16 + r]
            = pm * dv[n];
    }
  }
}

// ---------------------------------------------------------------------------
extern "C" void kernel_launch(void* const* d_in, const int* in_sizes, int n_in,
                              void* d_out, int out_size, void* d_ws, size_t ws_size,
                              hipStream_t stream) {
  const float* data = (const float*)d_in[0];   // [4096][512]
  const float* w1   = (const float*)d_in[1];   // [64000][512]
  float* out = (float*)d_out;                  // [2000][4096]

  signed char* wq = (signed char*)d_ws;                       // 32.77 MB
  signed char* dq = wq + (size_t)N_P * E_DIM;                 //  2.10 MB
  float* wsc = (float*)(dq + (size_t)B_Q * E_DIM);            // 256 KB
  float* dsc = wsc + N_P;                                     //  16 KB

  normq_kernel<<<N_P + B_Q, 128, 0, stream>>>(w1, data, wq, dq, wsc, dsc);
  gemm_max_kernel<<<(N_P / BM) * (B_Q / BN), 256, 0, stream>>>(wq, dq, wsc, dsc, out);
}